// Round 9
// baseline (596.546 us; speedup 1.0000x reference)
//
#include <hip/hip_runtime.h>
#include <math.h>

#define NN 1152
#define DD 64
#define NSK 2016
#define NB 16
#define NROWS (NB*1024)
#define GPARTS 6
#define KPARTS 6
#define VNBLK 32
#define VBLKS (VNBLK*KPARTS)   // 192 vproj GEMM blocks
#define TOFF (VBLKS + GPARTS)  // P-convert blocks
#define TBLKS 18

typedef short bf16x8 __attribute__((ext_vector_type(8)));
typedef short bf16x4 __attribute__((ext_vector_type(4)));
typedef float f32x4  __attribute__((ext_vector_type(4)));

__device__ __forceinline__ short bfr(float f){
  unsigned u = __float_as_uint(f);
  u += 0x7fffu + ((u >> 16) & 1u);
  return (short)(u >> 16);
}
__device__ __forceinline__ float htof(short h){
  return __uint_as_float(((unsigned)(unsigned short)h) << 16);
}

// ===== K1: vproj GEMM (0..191) + partial gram (192..197) + P->bf16/transpose (198..215) =====
__global__ __launch_bounds__(256) void k_pre(const float* __restrict__ cond, const float* __restrict__ W,
                                             float* __restrict__ vpart,
                                             const float* __restrict__ P, float* __restrict__ Gpart,
                                             short* __restrict__ Pbf, short* __restrict__ Ptbf){
  __shared__ float Ps[64*68];
  const int tid = threadIdx.x;
  if (blockIdx.x < VBLKS){
    const int nb = blockIdx.x / KPARTS;
    const int kp = blockIdx.x % KPARTS;
    const int lane = tid & 63, wid = tid >> 6;
    const int m = lane & 15, quad = lane >> 4;
    const int n0 = nb*64 + wid*16;
    if (n0 >= NSK) return;            // tail tiles of last N-block
    f32x4 acc = {0.f,0.f,0.f,0.f};
    const float* crow = &cond[m*NN + kp*192 + quad*8];
    const float* wrow = &W[(n0 + m)*NN + kp*192 + quad*8];
    #pragma unroll
    for (int c = 0; c < 6; ++c){
      const float4 ca = *(const float4*)(crow + c*32);
      const float4 cb = *(const float4*)(crow + c*32 + 4);
      const float4 wa = *(const float4*)(wrow + c*32);
      const float4 wb = *(const float4*)(wrow + c*32 + 4);
      bf16x8 a, b;
      const float cv[8] = {ca.x,ca.y,ca.z,ca.w,cb.x,cb.y,cb.z,cb.w};
      const float wv[8] = {wa.x,wa.y,wa.z,wa.w,wb.x,wb.y,wb.z,wb.w};
      #pragma unroll
      for (int j = 0; j < 8; ++j){
        const float xv = cv[j];
        a[j] = bfr(xv / (1.f + __expf(-xv)));
        b[j] = bfr(wv[j]);
      }
      acc = __builtin_amdgcn_mfma_f32_16x16x32_bf16(a, b, acc, 0, 0, 0);
    }
    #pragma unroll
    for (int r = 0; r < 4; ++r)
      vpart[(kp*16 + quad*4 + r)*NSK + n0 + m] = acc[r];
  } else if (blockIdx.x < TOFF){
    // ---- partial gram: block p covers rows p*192 .. p*192+191 (3 chunks of 64)
    const int p = blockIdx.x - VBLKS;
    const int lr = tid >> 4, lc = (tid & 15) * 4;
    const int ti = tid >> 4, tj = tid & 15;
    float acc[4][4];
    #pragma unroll
    for (int i=0;i<4;++i){
      #pragma unroll
      for (int j=0;j<4;++j) acc[i][j]=0.f;
    }
    for (int ch = 0; ch < 3; ++ch){
      const int nn0 = p*192 + ch*64;
      __syncthreads();
      #pragma unroll
      for (int ii = 0; ii < 4; ++ii){
        const float4 pv = *(const float4*)&P[(nn0 + lr + 16*ii)*DD + lc];
        *(float4*)&Ps[(lr + 16*ii)*68 + lc] = pv;
      }
      __syncthreads();
      for (int r = 0; r < 64; ++r){
        const float4 a = *(const float4*)&Ps[r*68 + ti*4];
        const float4 b = *(const float4*)&Ps[r*68 + tj*4];
        const float av[4] = {a.x,a.y,a.z,a.w};
        const float bv[4] = {b.x,b.y,b.z,b.w};
        #pragma unroll
        for (int i=0;i<4;++i){
          #pragma unroll
          for (int j=0;j<4;++j) acc[i][j] = fmaf(av[i], bv[j], acc[i][j]);
        }
      }
    }
    float* g = &Gpart[p*DD*DD];
    #pragma unroll
    for (int i=0;i<4;++i){
      float4 ov = make_float4(acc[i][0], acc[i][1], acc[i][2], acc[i][3]);
      *(float4*)&g[(ti*4+i)*DD + tj*4] = ov;
    }
  } else {
    // ---- P -> Pbf (row-major bf16) and Ptbf (transposed bf16 [64][1152])
    const int t = blockIdx.x - TOFF;
    const int n0 = t*64;
    for (int idx = tid; idx < 4096; idx += 256)
      Ps[(idx>>6)*68 + (idx&63)] = P[(n0 + (idx>>6))*DD + (idx&63)];
    __syncthreads();
    for (int idx = tid; idx < 4096; idx += 256){
      const int r = idx>>6, c = idx&63;
      Pbf[(n0+r)*DD + c] = bfr(Ps[r*68 + c]);
    }
    for (int idx = tid; idx < 4096; idx += 256){
      const int d = idx>>6, rr = idx&63;
      Ptbf[d*NN + n0 + rr] = bfr(Ps[rr*68 + d]);
    }
  }
}

// 512-thread 64x64 fp32 matmul: wave w owns rows (w&3)*16, cols (w>>2)*32
__device__ __forceinline__ void mmul68(const float* __restrict__ A, const float* __restrict__ B,
                                       float* __restrict__ C, int tid){
  __syncthreads();
  const int w = tid >> 6, lane = tid & 63;
  const int r0 = (w & 3) * 16 + (lane >> 3) * 2;
  const int c0 = (w >> 2) * 32 + (lane & 7) * 4;
  float acc[2][4];
  #pragma unroll
  for (int i=0;i<2;++i){
    #pragma unroll
    for (int j=0;j<4;++j) acc[i][j]=0.f;
  }
  for (int kq = 0; kq < 16; ++kq){
    float4 b[4];
    #pragma unroll
    for (int kk=0;kk<4;++kk) b[kk] = *(const float4*)&B[(kq*4+kk)*68 + c0];
    const float4 a0 = *(const float4*)&A[(r0    )*68 + kq*4];
    const float4 a1 = *(const float4*)&A[(r0 + 1)*68 + kq*4];
    const float av0[4] = {a0.x,a0.y,a0.z,a0.w};
    const float av1[4] = {a1.x,a1.y,a1.z,a1.w};
    #pragma unroll
    for (int kk=0;kk<4;++kk){
      acc[0][0] = fmaf(av0[kk], b[kk].x, acc[0][0]);
      acc[0][1] = fmaf(av0[kk], b[kk].y, acc[0][1]);
      acc[0][2] = fmaf(av0[kk], b[kk].z, acc[0][2]);
      acc[0][3] = fmaf(av0[kk], b[kk].w, acc[0][3]);
      acc[1][0] = fmaf(av1[kk], b[kk].x, acc[1][0]);
      acc[1][1] = fmaf(av1[kk], b[kk].y, acc[1][1]);
      acc[1][2] = fmaf(av1[kk], b[kk].z, acc[1][2]);
      acc[1][3] = fmaf(av1[kk], b[kk].w, acc[1][3]);
    }
  }
  *(float4*)&C[(r0    )*68 + c0] = make_float4(acc[0][0],acc[0][1],acc[0][2],acc[0][3]);
  *(float4*)&C[(r0 + 1)*68 + c0] = make_float4(acc[1][0],acc[1][1],acc[1][2],acc[1][3]);
  __syncthreads();
}

// Same but writes bf16 (stride 72) — final w' stage.
__device__ __forceinline__ void mmul68_w(const float* __restrict__ A, const float* __restrict__ B,
                                         short* __restrict__ Wb, int tid){
  __syncthreads();
  const int w = tid >> 6, lane = tid & 63;
  const int r0 = (w & 3) * 16 + (lane >> 3) * 2;
  const int c0 = (w >> 2) * 32 + (lane & 7) * 4;
  float acc[2][4];
  #pragma unroll
  for (int i=0;i<2;++i){
    #pragma unroll
    for (int j=0;j<4;++j) acc[i][j]=0.f;
  }
  for (int kq = 0; kq < 16; ++kq){
    float4 b[4];
    #pragma unroll
    for (int kk=0;kk<4;++kk) b[kk] = *(const float4*)&B[(kq*4+kk)*68 + c0];
    const float4 a0 = *(const float4*)&A[(r0    )*68 + kq*4];
    const float4 a1 = *(const float4*)&A[(r0 + 1)*68 + kq*4];
    const float av0[4] = {a0.x,a0.y,a0.z,a0.w};
    const float av1[4] = {a1.x,a1.y,a1.z,a1.w};
    #pragma unroll
    for (int kk=0;kk<4;++kk){
      acc[0][0] = fmaf(av0[kk], b[kk].x, acc[0][0]);
      acc[0][1] = fmaf(av0[kk], b[kk].y, acc[0][1]);
      acc[0][2] = fmaf(av0[kk], b[kk].z, acc[0][2]);
      acc[0][3] = fmaf(av0[kk], b[kk].w, acc[0][3]);
      acc[1][0] = fmaf(av1[kk], b[kk].x, acc[1][0]);
      acc[1][1] = fmaf(av1[kk], b[kk].y, acc[1][1]);
      acc[1][2] = fmaf(av1[kk], b[kk].z, acc[1][2]);
      acc[1][3] = fmaf(av1[kk], b[kk].w, acc[1][3]);
    }
  }
  bf16x4 p0, p1;
  #pragma unroll
  for (int j=0;j<4;++j){ p0[j] = bfr(acc[0][j]); p1[j] = bfr(acc[1][j]); }
  *(bf16x4*)&Wb[(r0    )*72 + c0] = p0;
  *(bf16x4*)&Wb[(r0 + 1)*72 + c0] = p1;
  __syncthreads();
}

// ===== K2: expm (blocks 0..15) + QR+Rinv (block 16) — no co-tenant contention =====
__global__ __launch_bounds__(512,1) void k_exp(const float* __restrict__ Gpart, const float* __restrict__ P,
                                               const float* __restrict__ vpart, const float* __restrict__ bias,
                                               float* __restrict__ Mg, float* __restrict__ Rinvg){
  __shared__ float Bs[64*68], B2[64*68], B3[64*68], Tb[64*68], Xb[64*68];
  __shared__ float red[512];
  __shared__ float scl_s;
  __shared__ int   ssh_s;
  const int tid = threadIdx.x;
  if (blockIdx.x == NB){
    // ---------- QR (R into Bs) then register-unrolled back-substitution for Rinv ----------
    if (tid < 64){
      const int j = tid;
      float Gc[DD], Wc[DD], Rc[DD];
      #pragma unroll
      for (int i = 0; i < DD; ++i){
        float g = 0.f;
        #pragma unroll
        for (int p = 0; p < GPARTS; ++p) g += Gpart[p*4096 + i*DD + j];
        Gc[i] = g;
        Wc[i] = P[i*DD + j];
      }
      #pragma unroll
      for (int k = 0; k < DD; ++k){
        const float gkk = __shfl(Gc[k], k);
        const float wkk = __shfl(Wc[k], k);
        const float beta = (wkk >= 0.f) ? -sqrtf(gkk) : sqrtf(gkk);
        const float wkj = Wc[k];
        const float dj  = Gc[k] - beta*wkj;
        const float cj  = dj / (beta*(beta - wkk));
        float rkj = wkj + dj/beta;
        if (j == k) rkj = beta;
        if (j <  k) rkj = 0.f;
        Rc[k] = rkj;
        #pragma unroll
        for (int i = k+1; i < DD; ++i){
          const float wik = __shfl(Wc[i], k);
          const float rki = __shfl(rkj, i);
          Wc[i] = fmaf(-cj,  wik, Wc[i]);
          Gc[i] = fmaf(-rki, rkj, Gc[i]);
        }
      }
      #pragma unroll
      for (int i = 0; i < DD; ++i) Bs[i*68 + j] = Rc[i];
    }
    __syncthreads();
    if (tid < 64){
      const int j = tid;
      float Xc[DD];
      #pragma unroll
      for (int i = DD-1; i >= 0; --i){
        float acc = (i==j) ? 1.f : 0.f;
        #pragma unroll
        for (int l = i+1; l < DD; ++l)
          acc = fmaf(-Bs[i*68 + l], Xc[l], acc);
        Xc[i] = acc / Bs[i*68 + i];
      }
      #pragma unroll
      for (int i = 0; i < DD; ++i)
        Rinvg[i*DD + j] = Xc[i];
    }
    return;
  }
  // ---------- expm (fp32, proven path) ----------
  const int b = blockIdx.x;
  for (int idx = tid; idx < 64*64; idx += 512)
    Xb[(idx>>6)*68 + (idx&63)] = 0.f;
  __syncthreads();
  for (int idx = tid; idx < NSK; idx += 512){
    int i = (int)((127.0f - sqrtf(16129.0f - 8.0f*(float)idx)) * 0.5f);
    while (i*(127 - i)/2 > idx) --i;
    while ((i+1)*(127 - (i+1))/2 <= idx) ++i;
    const int jj = idx - i*(127 - i)/2 + i + 1;
    float val = bias[idx];
    #pragma unroll
    for (int p = 0; p < KPARTS; ++p) val += vpart[(p*16 + b)*NSK + idx];
    Xb[i*68 + jj] = val;
    Xb[jj*68 + i] = -val;
  }
  __syncthreads();
  {
    const int c = tid & 63, g = tid >> 6;
    float s = 0.f;
    for (int r = g*8; r < g*8 + 8; ++r) s += fabsf(Xb[r*68 + c]);
    red[g*64 + c] = s;
    __syncthreads();
    if (tid < 64){
      float cs = 0.f;
      #pragma unroll
      for (int g2 = 0; g2 < 8; ++g2) cs += red[g2*64 + tid];
      #pragma unroll
      for (int off = 32; off > 0; off >>= 1) cs = fmaxf(cs, __shfl_xor(cs, off));
      if (tid == 0){
        int s2 = 0; float scale = 1.f;
        float nrm = cs;
        while (nrm > 1.0f && s2 < 40){ nrm *= 0.5f; scale *= 0.5f; ++s2; }
        ssh_s = s2; scl_s = scale;
      }
    }
    __syncthreads();
  }
  const float scale = scl_s;
  const int   sq    = ssh_s;
  for (int idx = tid; idx < 64*64; idx += 512){
    const int i = idx>>6, jj = idx&63;
    Bs[i*68 + jj] = Xb[i*68 + jj] * scale;
  }
  mmul68(Bs, Bs, B2, tid);
  mmul68(B2, Bs, B3, tid);
  for (int idx = tid; idx < 64*64; idx += 512){
    const int i = idx>>6, jj = idx&63;
    const int o = i*68 + jj;
    Tb[o] = (i==jj ? (1.f/720.f) : 0.f) + Bs[o]*(1.f/5040.f) + B2[o]*(1.f/40320.f) + B3[o]*(1.f/362880.f);
  }
  mmul68(B3, Tb, Xb, tid);              // X = B3*T
  for (int idx = tid; idx < 64*64; idx += 512){
    const int i = idx>>6, jj = idx&63;
    const int o = i*68 + jj;
    Xb[o] += (i==jj ? (1.f/6.f) : 0.f) + Bs[o]*(1.f/24.f) + B2[o]*(1.f/120.f);
  }
  mmul68(B3, Xb, Tb, tid);              // T = B3*X
  for (int idx = tid; idx < 64*64; idx += 512){
    const int i = idx>>6, jj = idx&63;
    const int o = i*68 + jj;
    Tb[o] += (i==jj ? 1.f : 0.f) + Bs[o] + B2[o]*0.5f;   // + G0
  }
  float* cur = Tb;
  float* oth = Xb;
  for (int r = 0; r < sq; ++r){
    mmul68(cur, cur, oth, tid);
    float* t = cur; cur = oth; oth = t;
  }
  for (int idx = tid; idx < 64*64; idx += 512){
    const int i = idx>>6, jj = idx&63;
    Mg[b*4096 + idx] = cur[i*68 + jj] - (i==jj ? 1.f : 0.f);
  }
}

// ===== K3 fused x-path: z = x.P ; w' = ((z.Rinv).M).Rinv^T ; out = x + w'.P^T =====
__global__ __launch_bounds__(512,1) void k_all(const float* __restrict__ x, const short* __restrict__ Ptbf,
                                               const short* __restrict__ Pbf, const float* __restrict__ Mg,
                                               const float* __restrict__ Rinvg, float* __restrict__ out){
  __shared__ float zs[64*68], ts[64*68];
  __shared__ float Ri[64*68], Ric[64*68], Ms[64*68];
  __shared__ short wbf[64*72];
  __shared__ float os[2][64*68];
  const int tid  = threadIdx.x;
  const int lane = tid & 63, wid = tid >> 6;
  const int row0 = blockIdx.x * 64;
  const int bb   = blockIdx.x >> 4;
  const int m    = lane & 15, quad = lane >> 4;

  // stage Rinv (rm), Rinv^T (rm-of-transpose), M
  for (int idx = tid; idx < 4096; idx += 512){
    const int r = idx>>6, c = idx&63;
    Ri [r*68 + c] = Rinvg[r*DD + c];
    Ric[r*68 + c] = Rinvg[c*DD + r];
    Ms [r*68 + c] = Mg[bb*4096 + idx];
  }

  // ---- P1: z = x_tile @ P  (8 waves; proven y-GEMM pattern; z stays fp32)
  {
    const int r0 = (wid & 3) * 16;
    const int c0 = (wid >> 2) * 32;
    f32x4 acc0 = {0.f,0.f,0.f,0.f}, acc1 = {0.f,0.f,0.f,0.f};
    const float* xrow = &x[(row0 + r0 + m)*NN + quad*8];
    const short* ut0  = &Ptbf[(c0      + m)*NN + quad*8];
    const short* ut1  = &Ptbf[(c0 + 16 + m)*NN + quad*8];
    float4 xa = *(const float4*)(xrow);
    float4 xb = *(const float4*)(xrow + 4);
    bf16x8 b0 = *(const bf16x8*)(ut0);
    bf16x8 b1 = *(const bf16x8*)(ut1);
    for (int kc = 0; kc < NN; kc += 32){
      float4 nxa, nxb; bf16x8 nb0, nb1;
      if (kc + 32 < NN){
        nxa = *(const float4*)(xrow + kc + 32);
        nxb = *(const float4*)(xrow + kc + 36);
        nb0 = *(const bf16x8*)(ut0 + kc + 32);
        nb1 = *(const bf16x8*)(ut1 + kc + 32);
      }
      bf16x8 a;
      a[0]=bfr(xa.x); a[1]=bfr(xa.y); a[2]=bfr(xa.z); a[3]=bfr(xa.w);
      a[4]=bfr(xb.x); a[5]=bfr(xb.y); a[6]=bfr(xb.z); a[7]=bfr(xb.w);
      acc0 = __builtin_amdgcn_mfma_f32_16x16x32_bf16(a, b0, acc0, 0, 0, 0);
      acc1 = __builtin_amdgcn_mfma_f32_16x16x32_bf16(a, b1, acc1, 0, 0, 0);
      xa = nxa; xb = nxb; b0 = nb0; b1 = nb1;
    }
    #pragma unroll
    for (int q = 0; q < 4; ++q){
      zs[(r0 + quad*4 + q)*68 + c0      + m] = acc0[q];
      zs[(r0 + quad*4 + q)*68 + c0 + 16 + m] = acc1[q];
    }
  }

  // ---- P2: w' = ((z @ Rinv) @ M) @ Rinv^T  (fp32; 3 LDS matmuls)
  mmul68  (zs, Ri,  ts, tid);    // t = z @ Rinv
  mmul68  (ts, Ms,  zs, tid);    // u = t @ M      (z dead, reuse)
  mmul68_w(zs, Ric, wbf, tid);   // w' = u @ Rinv^T -> bf16

  // ---- P3: out = x + w' @ P^T  (18 col-chunks of 64; coalesced via os dbuf)
  const int rt  = wid & 3;
  const int ctA = wid >> 2;                 // wave covers col-tiles ctA and ctA+2
  bf16x8 wa0 = *(const bf16x8*)&wbf[(rt*16 + m)*72 +      quad*8];
  bf16x8 wa1 = *(const bf16x8*)&wbf[(rt*16 + m)*72 + 32 + quad*8];
  for (int it = 0; it < 18; ++it){
    float* ob = os[it & 1];
    #pragma unroll
    for (int half = 0; half < 2; ++half){
      const int ct  = ctA + half*2;
      const int n0c = it*64 + ct*16;
      const bf16x8 ub0 = *(const bf16x8*)&Pbf[(n0c + m)*DD +      quad*8];
      const bf16x8 ub1 = *(const bf16x8*)&Pbf[(n0c + m)*DD + 32 + quad*8];
      f32x4 acc = {0.f,0.f,0.f,0.f};
      acc = __builtin_amdgcn_mfma_f32_16x16x32_bf16(wa0, ub0, acc, 0, 0, 0);
      acc = __builtin_amdgcn_mfma_f32_16x16x32_bf16(wa1, ub1, acc, 0, 0, 0);
      #pragma unroll
      for (int q = 0; q < 4; ++q)
        ob[(rt*16 + quad*4 + q)*68 + ct*16 + m] = acc[q];
    }
    __syncthreads();
    #pragma unroll
    for (int p = 0; p < 2; ++p){
      const int idx = tid + p*512;
      const int er = idx >> 4, ec = (idx & 15) * 4;
      const float4 xv = *(const float4*)&x[(row0 + er)*NN + it*64 + ec];
      const float4 ov = *(const float4*)&ob[er*68 + ec];
      *(float4*)&out[(row0 + er)*NN + it*64 + ec] =
          make_float4(xv.x + ov.x, xv.y + ov.y, xv.z + ov.z, xv.w + ov.w);
    }
  }
}

extern "C" void kernel_launch(void* const* d_in, const int* in_sizes, int n_in,
                              void* d_out, int out_size, void* d_ws, size_t ws_size,
                              hipStream_t stream) {
  const float* x    = (const float*)d_in[0];
  const float* cond = (const float*)d_in[1];
  const float* P    = (const float*)d_in[2];
  const float* W    = (const float*)d_in[3];
  const float* bias = (const float*)d_in[4];
  float* out = (float*)d_out;
  float* ws  = (float*)d_ws;

  float* Gpart = ws;                      // 24576 floats
  float* vpart = ws + 24576;              // 193536 floats
  float* Mg    = ws + 218112;             // 65536 floats
  float* Rinvg = ws + 283648;             // 4096 floats
  short* Pbf   = (short*)(ws + 287744);   // 1152*64 bf16 = 36864 floats
  short* Ptbf  = (short*)(ws + 324608);   // 64*1152 bf16 = 36864 floats

  hipLaunchKernelGGL(k_pre, dim3(VBLKS + GPARTS + TBLKS), dim3(256), 0, stream,
                     cond, W, vpart, P, Gpart, Pbf, Ptbf);
  hipLaunchKernelGGL(k_exp, dim3(NB + 1), dim3(512), 0, stream,
                     Gpart, P, vpart, bias, Mg, Rinvg);
  hipLaunchKernelGGL(k_all, dim3(NROWS/64), dim3(512), 0, stream,
                     x, Ptbf, Pbf, Mg, Rinvg, out);
}

// Round 10
// 237.530 us; speedup vs baseline: 2.5115x; 2.5115x over previous
//
#include <hip/hip_runtime.h>
#include <math.h>

#define NN 1152
#define DD 64
#define NSK 2016
#define NB 16
#define NROWS (NB*1024)
#define GPARTS 6
#define KPARTS 6
#define VNBLK 32
#define VBLKS (VNBLK*KPARTS)   // 192 vproj GEMM blocks
#define TOFF (VBLKS + GPARTS)  // P-convert blocks
#define TBLKS 18

typedef short bf16x8 __attribute__((ext_vector_type(8)));
typedef short bf16x4 __attribute__((ext_vector_type(4)));
typedef float f32x4  __attribute__((ext_vector_type(4)));

__device__ __forceinline__ short bfr(float f){
  unsigned u = __float_as_uint(f);
  u += 0x7fffu + ((u >> 16) & 1u);
  return (short)(u >> 16);
}
__device__ __forceinline__ float htof(short h){
  return __uint_as_float(((unsigned)(unsigned short)h) << 16);
}

// ===== K1: vproj GEMM (0..191) + partial gram (192..197) + P->bf16/transpose (198..215) =====
__global__ __launch_bounds__(256) void k_pre(const float* __restrict__ cond, const float* __restrict__ W,
                                             float* __restrict__ vpart,
                                             const float* __restrict__ P, float* __restrict__ Gpart,
                                             short* __restrict__ Pbf, short* __restrict__ Ptbf){
  __shared__ float Ps[64*68];
  const int tid = threadIdx.x;
  if (blockIdx.x < VBLKS){
    const int nb = blockIdx.x / KPARTS;
    const int kp = blockIdx.x % KPARTS;
    const int lane = tid & 63, wid = tid >> 6;
    const int m = lane & 15, quad = lane >> 4;
    const int n0 = nb*64 + wid*16;
    if (n0 >= NSK) return;            // tail tiles of last N-block
    f32x4 acc = {0.f,0.f,0.f,0.f};
    const float* crow = &cond[m*NN + kp*192 + quad*8];
    const float* wrow = &W[(n0 + m)*NN + kp*192 + quad*8];
    #pragma unroll
    for (int c = 0; c < 6; ++c){
      const float4 ca = *(const float4*)(crow + c*32);
      const float4 cb = *(const float4*)(crow + c*32 + 4);
      const float4 wa = *(const float4*)(wrow + c*32);
      const float4 wb = *(const float4*)(wrow + c*32 + 4);
      bf16x8 a, b;
      const float cv[8] = {ca.x,ca.y,ca.z,ca.w,cb.x,cb.y,cb.z,cb.w};
      const float wv[8] = {wa.x,wa.y,wa.z,wa.w,wb.x,wb.y,wb.z,wb.w};
      #pragma unroll
      for (int j = 0; j < 8; ++j){
        const float xv = cv[j];
        a[j] = bfr(xv / (1.f + __expf(-xv)));
        b[j] = bfr(wv[j]);
      }
      acc = __builtin_amdgcn_mfma_f32_16x16x32_bf16(a, b, acc, 0, 0, 0);
    }
    #pragma unroll
    for (int r = 0; r < 4; ++r)
      vpart[(kp*16 + quad*4 + r)*NSK + n0 + m] = acc[r];
  } else if (blockIdx.x < TOFF){
    // ---- partial gram: block p covers rows p*192 .. p*192+191 (3 chunks of 64)
    const int p = blockIdx.x - VBLKS;
    const int lr = tid >> 4, lc = (tid & 15) * 4;
    const int ti = tid >> 4, tj = tid & 15;
    float acc[4][4];
    #pragma unroll
    for (int i=0;i<4;++i){
      #pragma unroll
      for (int j=0;j<4;++j) acc[i][j]=0.f;
    }
    for (int ch = 0; ch < 3; ++ch){
      const int nn0 = p*192 + ch*64;
      __syncthreads();
      #pragma unroll
      for (int ii = 0; ii < 4; ++ii){
        const float4 pv = *(const float4*)&P[(nn0 + lr + 16*ii)*DD + lc];
        *(float4*)&Ps[(lr + 16*ii)*68 + lc] = pv;
      }
      __syncthreads();
      for (int r = 0; r < 64; ++r){
        const float4 a = *(const float4*)&Ps[r*68 + ti*4];
        const float4 b = *(const float4*)&Ps[r*68 + tj*4];
        const float av[4] = {a.x,a.y,a.z,a.w};
        const float bv[4] = {b.x,b.y,b.z,b.w};
        #pragma unroll
        for (int i=0;i<4;++i){
          #pragma unroll
          for (int j=0;j<4;++j) acc[i][j] = fmaf(av[i], bv[j], acc[i][j]);
        }
      }
    }
    float* g = &Gpart[p*DD*DD];
    #pragma unroll
    for (int i=0;i<4;++i){
      float4 ov = make_float4(acc[i][0], acc[i][1], acc[i][2], acc[i][3]);
      *(float4*)&g[(ti*4+i)*DD + tj*4] = ov;
    }
  } else {
    // ---- P -> Pbf (row-major bf16) and Ptbf (transposed bf16 [64][1152])
    const int t = blockIdx.x - TOFF;
    const int n0 = t*64;
    for (int idx = tid; idx < 4096; idx += 256)
      Ps[(idx>>6)*68 + (idx&63)] = P[(n0 + (idx>>6))*DD + (idx&63)];
    __syncthreads();
    for (int idx = tid; idx < 4096; idx += 256){
      const int r = idx>>6, c = idx&63;
      Pbf[(n0+r)*DD + c] = bfr(Ps[r*68 + c]);
    }
    for (int idx = tid; idx < 4096; idx += 256){
      const int d = idx>>6, rr = idx&63;
      Ptbf[d*NN + n0 + rr] = bfr(Ps[rr*68 + d]);
    }
  }
}

// 512-thread 64x64 fp32 matmul (expm): wave w owns rows (w&3)*16, cols (w>>2)*32
__device__ __forceinline__ void mmul68(const float* __restrict__ A, const float* __restrict__ B,
                                       float* __restrict__ C, int tid){
  __syncthreads();
  const int w = tid >> 6, lane = tid & 63;
  const int r0 = (w & 3) * 16 + (lane >> 3) * 2;
  const int c0 = (w >> 2) * 32 + (lane & 7) * 4;
  float acc[2][4];
  #pragma unroll
  for (int i=0;i<2;++i){
    #pragma unroll
    for (int j=0;j<4;++j) acc[i][j]=0.f;
  }
  float4 b0 = *(const float4*)&B[0*68 + c0];
  float4 b1 = *(const float4*)&B[1*68 + c0];
  float4 b2 = *(const float4*)&B[2*68 + c0];
  float4 b3 = *(const float4*)&B[3*68 + c0];
  float4 a0 = *(const float4*)&A[(r0    )*68];
  float4 a1 = *(const float4*)&A[(r0 + 1)*68];
  for (int kq = 0; kq < 16; ++kq){
    float4 nb0, nb1, nb2, nb3, na0, na1;
    if (kq < 15){
      const int k4 = (kq+1)*4;
      nb0 = *(const float4*)&B[(k4+0)*68 + c0];
      nb1 = *(const float4*)&B[(k4+1)*68 + c0];
      nb2 = *(const float4*)&B[(k4+2)*68 + c0];
      nb3 = *(const float4*)&B[(k4+3)*68 + c0];
      na0 = *(const float4*)&A[(r0    )*68 + k4];
      na1 = *(const float4*)&A[(r0 + 1)*68 + k4];
    }
    const float av0[4] = {a0.x,a0.y,a0.z,a0.w};
    const float av1[4] = {a1.x,a1.y,a1.z,a1.w};
    const float4 bb[4] = {b0,b1,b2,b3};
    #pragma unroll
    for (int kk=0;kk<4;++kk){
      acc[0][0] = fmaf(av0[kk], bb[kk].x, acc[0][0]);
      acc[0][1] = fmaf(av0[kk], bb[kk].y, acc[0][1]);
      acc[0][2] = fmaf(av0[kk], bb[kk].z, acc[0][2]);
      acc[0][3] = fmaf(av0[kk], bb[kk].w, acc[0][3]);
      acc[1][0] = fmaf(av1[kk], bb[kk].x, acc[1][0]);
      acc[1][1] = fmaf(av1[kk], bb[kk].y, acc[1][1]);
      acc[1][2] = fmaf(av1[kk], bb[kk].z, acc[1][2]);
      acc[1][3] = fmaf(av1[kk], bb[kk].w, acc[1][3]);
    }
    b0 = nb0; b1 = nb1; b2 = nb2; b3 = nb3; a0 = na0; a1 = na1;
  }
  *(float4*)&C[(r0    )*68 + c0] = make_float4(acc[0][0],acc[0][1],acc[0][2],acc[0][3]);
  *(float4*)&C[(r0 + 1)*68 + c0] = make_float4(acc[1][0],acc[1][1],acc[1][2],acc[1][3]);
  __syncthreads();
}

// ===== K2 fused: expm (0..15) + QR-only (block 16, writes R) + y = x@P GEMM (17..272) =====
__global__ __launch_bounds__(512,1) void k_fused(const float* __restrict__ Gpart, const float* __restrict__ P,
                                                 const float* __restrict__ vpart, const float* __restrict__ bias,
                                                 float* __restrict__ Mg, float* __restrict__ Rg,
                                                 const float* __restrict__ x, const short* __restrict__ Ptbf,
                                                 short* __restrict__ ybf){
  __shared__ float Bs[64*68], B2[64*68], B3[64*68], Tb[64*68], Xb[64*68];
  __shared__ float red[512];
  __shared__ float scl_s;
  __shared__ int   ssh_s;
  const int tid = threadIdx.x;
  if (blockIdx.x > NB){
    // ---------- y = x @ P  (64-row tile, 8 waves) ----------
    const int lane = tid & 63, wid = tid >> 6;
    const int row0 = (blockIdx.x - NB - 1) * 64;
    const int m    = lane & 15, quad = lane >> 4;
    const int r0 = (wid & 3) * 16;
    const int c0 = (wid >> 2) * 32;
    f32x4 acc0 = {0.f,0.f,0.f,0.f}, acc1 = {0.f,0.f,0.f,0.f};
    const float* xrow = &x[(row0 + r0 + m)*NN + quad*8];
    const short* ut0  = &Ptbf[(c0      + m)*NN + quad*8];
    const short* ut1  = &Ptbf[(c0 + 16 + m)*NN + quad*8];
    float4 xa = *(const float4*)(xrow);
    float4 xb = *(const float4*)(xrow + 4);
    bf16x8 b0 = *(const bf16x8*)(ut0);
    bf16x8 b1 = *(const bf16x8*)(ut1);
    for (int kc = 0; kc < NN; kc += 32){
      float4 nxa, nxb; bf16x8 nb0, nb1;
      if (kc + 32 < NN){
        nxa = *(const float4*)(xrow + kc + 32);
        nxb = *(const float4*)(xrow + kc + 36);
        nb0 = *(const bf16x8*)(ut0 + kc + 32);
        nb1 = *(const bf16x8*)(ut1 + kc + 32);
      }
      bf16x8 a;
      a[0]=bfr(xa.x); a[1]=bfr(xa.y); a[2]=bfr(xa.z); a[3]=bfr(xa.w);
      a[4]=bfr(xb.x); a[5]=bfr(xb.y); a[6]=bfr(xb.z); a[7]=bfr(xb.w);
      acc0 = __builtin_amdgcn_mfma_f32_16x16x32_bf16(a, b0, acc0, 0, 0, 0);
      acc1 = __builtin_amdgcn_mfma_f32_16x16x32_bf16(a, b1, acc1, 0, 0, 0);
      xa = nxa; xb = nxb; b0 = nb0; b1 = nb1;
    }
    #pragma unroll
    for (int q = 0; q < 4; ++q){
      ybf[(row0 + r0 + quad*4 + q)*DD + c0      + m] = bfr(acc0[q]);
      ybf[(row0 + r0 + quad*4 + q)*DD + c0 + 16 + m] = bfr(acc1[q]);
    }
    return;
  }
  if (blockIdx.x == NB){
    // ---------- QR only (rounds 2-4 proven): write R to global ----------
    if (tid < 64){
      const int j = tid;
      float Gc[DD], Wc[DD], Rc[DD];
      #pragma unroll
      for (int i = 0; i < DD; ++i){
        float g = 0.f;
        #pragma unroll
        for (int p = 0; p < GPARTS; ++p) g += Gpart[p*4096 + i*DD + j];
        Gc[i] = g;
        Wc[i] = P[i*DD + j];
      }
      #pragma unroll
      for (int k = 0; k < DD; ++k){
        const float gkk = __shfl(Gc[k], k);
        const float wkk = __shfl(Wc[k], k);
        const float beta = (wkk >= 0.f) ? -sqrtf(gkk) : sqrtf(gkk);
        const float wkj = Wc[k];
        const float dj  = Gc[k] - beta*wkj;
        const float cj  = dj / (beta*(beta - wkk));
        float rkj = wkj + dj/beta;
        if (j == k) rkj = beta;
        if (j <  k) rkj = 0.f;
        Rc[k] = rkj;
        #pragma unroll
        for (int i = k+1; i < DD; ++i){
          const float wik = __shfl(Wc[i], k);
          const float rki = __shfl(rkj, i);
          Wc[i] = fmaf(-cj,  wik, Wc[i]);
          Gc[i] = fmaf(-rki, rkj, Gc[i]);
        }
      }
      #pragma unroll
      for (int i = 0; i < DD; ++i) Rg[i*DD + j] = Rc[i];
    }
    return;
  }
  // ---------- expm (fp32, proven path) ----------
  const int b = blockIdx.x;
  for (int idx = tid; idx < 64*64; idx += 512)
    Xb[(idx>>6)*68 + (idx&63)] = 0.f;
  __syncthreads();
  for (int idx = tid; idx < NSK; idx += 512){
    int i = (int)((127.0f - sqrtf(16129.0f - 8.0f*(float)idx)) * 0.5f);
    while (i*(127 - i)/2 > idx) --i;
    while ((i+1)*(127 - (i+1))/2 <= idx) ++i;
    const int jj = idx - i*(127 - i)/2 + i + 1;
    float val = bias[idx];
    #pragma unroll
    for (int p = 0; p < KPARTS; ++p) val += vpart[(p*16 + b)*NSK + idx];
    Xb[i*68 + jj] = val;
    Xb[jj*68 + i] = -val;
  }
  __syncthreads();
  {
    const int c = tid & 63, g = tid >> 6;
    float s = 0.f;
    for (int r = g*8; r < g*8 + 8; ++r) s += fabsf(Xb[r*68 + c]);
    red[g*64 + c] = s;
    __syncthreads();
    if (tid < 64){
      float cs = 0.f;
      #pragma unroll
      for (int g2 = 0; g2 < 8; ++g2) cs += red[g2*64 + tid];
      #pragma unroll
      for (int off = 32; off > 0; off >>= 1) cs = fmaxf(cs, __shfl_xor(cs, off));
      if (tid == 0){
        int s2 = 0; float scale = 1.f;
        float nrm = cs;
        while (nrm > 1.0f && s2 < 40){ nrm *= 0.5f; scale *= 0.5f; ++s2; }
        ssh_s = s2; scl_s = scale;
      }
    }
    __syncthreads();
  }
  const float scale = scl_s;
  const int   sq    = ssh_s;
  for (int idx = tid; idx < 64*64; idx += 512){
    const int i = idx>>6, jj = idx&63;
    Bs[i*68 + jj] = Xb[i*68 + jj] * scale;
  }
  mmul68(Bs, Bs, B2, tid);
  mmul68(B2, Bs, B3, tid);
  for (int idx = tid; idx < 64*64; idx += 512){
    const int i = idx>>6, jj = idx&63;
    const int o = i*68 + jj;
    Tb[o] = (i==jj ? (1.f/720.f) : 0.f) + Bs[o]*(1.f/5040.f) + B2[o]*(1.f/40320.f) + B3[o]*(1.f/362880.f);
  }
  mmul68(B3, Tb, Xb, tid);              // X = B3*T
  for (int idx = tid; idx < 64*64; idx += 512){
    const int i = idx>>6, jj = idx&63;
    const int o = i*68 + jj;
    Xb[o] += (i==jj ? (1.f/6.f) : 0.f) + Bs[o]*(1.f/24.f) + B2[o]*(1.f/120.f);
  }
  mmul68(B3, Xb, Tb, tid);              // T = B3*X
  for (int idx = tid; idx < 64*64; idx += 512){
    const int i = idx>>6, jj = idx&63;
    const int o = i*68 + jj;
    Tb[o] += (i==jj ? 1.f : 0.f) + Bs[o] + B2[o]*0.5f;   // + G0
  }
  float* cur = Tb;
  float* oth = Xb;
  for (int r = 0; r < sq; ++r){
    mmul68(cur, cur, oth, tid);
    float* t = cur; cur = oth; oth = t;
  }
  for (int idx = tid; idx < 64*64; idx += 512){
    const int i = idx>>6, jj = idx&63;
    Mg[b*4096 + idx] = cur[i*68 + jj] - (i==jj ? 1.f : 0.f);
  }
}

// ===== K3: Rinv solve (per-block, k_solveU pattern) + K_b = Rinv*(E-I)*Rinv^T =====
__global__ __launch_bounds__(256) void k_kmat(const float* __restrict__ Rg, const float* __restrict__ Mg,
                                              float* __restrict__ Kg){
  __shared__ float Ri[64*68], Ms[64*68], Ts[64*68];
  __shared__ float rd[64];
  const int b = blockIdx.x, tid = threadIdx.x;
  float* Rf = Ts;   // flat R staging [r*64 + c], dead after solve
  for (int idx = tid; idx < 4096; idx += 256){
    Rf[idx] = Rg[idx];
    Ms[(idx>>6)*68 + (idx&63)] = Mg[b*4096 + idx];
  }
  __syncthreads();
  if (tid < 64) rd[tid] = 1.f / Rf[tid*DD + tid];
  __syncthreads();
  // thread j solves row j of Rinv: x.R = e_j (forward substitution, registers)
  if (tid < 64){
    float u[DD];
    #pragma unroll
    for (int j = 0; j < DD; ++j){
      float s0 = (tid == j) ? 1.f : 0.f, s1 = 0.f;
      #pragma unroll
      for (int l = 0; l + 1 < j; l += 2){
        s0 = fmaf(-u[l],   Rf[l*DD + j],     s0);
        s1 = fmaf(-u[l+1], Rf[(l+1)*DD + j], s1);
      }
      if (j & 1) s0 = fmaf(-u[j-1], Rf[(j-1)*DD + j], s0);
      u[j] = (s0 + s1) * rd[j];
    }
    #pragma unroll
    for (int c = 0; c < DD; ++c) Ri[tid*68 + c] = u[c];
  }
  __syncthreads();
  const int ti = tid >> 4, tj = tid & 15;
  // Ts = Ri * Ms  (overwrites flat R — dead)
  {
    float acc[4][4];
    #pragma unroll
    for (int i=0;i<4;++i){
      #pragma unroll
      for (int j=0;j<4;++j) acc[i][j]=0.f;
    }
    for (int kq = 0; kq < 16; ++kq){
      float4 a[4], bm[4];
      #pragma unroll
      for (int i=0;i<4;++i) a[i] = *(const float4*)&Ri[(ti*4+i)*68 + kq*4];
      #pragma unroll
      for (int kk=0;kk<4;++kk) bm[kk] = *(const float4*)&Ms[(kq*4+kk)*68 + tj*4];
      #pragma unroll
      for (int i=0;i<4;++i){
        const float av[4] = {a[i].x,a[i].y,a[i].z,a[i].w};
        #pragma unroll
        for (int kk=0;kk<4;++kk){
          acc[i][0] = fmaf(av[kk], bm[kk].x, acc[i][0]);
          acc[i][1] = fmaf(av[kk], bm[kk].y, acc[i][1]);
          acc[i][2] = fmaf(av[kk], bm[kk].z, acc[i][2]);
          acc[i][3] = fmaf(av[kk], bm[kk].w, acc[i][3]);
        }
      }
    }
    __syncthreads();
    #pragma unroll
    for (int i=0;i<4;++i)
      *(float4*)&Ts[(ti*4+i)*68 + tj*4] = make_float4(acc[i][0],acc[i][1],acc[i][2],acc[i][3]);
    __syncthreads();
  }
  // K = Ts * Ri^T  (K[r][c] = sum_k Ts[r][k]*Ri[c][k])
  {
    float acc[4][4];
    #pragma unroll
    for (int i=0;i<4;++i){
      #pragma unroll
      for (int j=0;j<4;++j) acc[i][j]=0.f;
    }
    for (int kq = 0; kq < 16; ++kq){
      float4 a[4], bt[4];
      #pragma unroll
      for (int i=0;i<4;++i) a[i] = *(const float4*)&Ts[(ti*4+i)*68 + kq*4];
      #pragma unroll
      for (int j=0;j<4;++j) bt[j] = *(const float4*)&Ri[(tj*4+j)*68 + kq*4];
      #pragma unroll
      for (int i=0;i<4;++i){
        #pragma unroll
        for (int j=0;j<4;++j){
          acc[i][j] = fmaf(a[i].x, bt[j].x, acc[i][j]);
          acc[i][j] = fmaf(a[i].y, bt[j].y, acc[i][j]);
          acc[i][j] = fmaf(a[i].z, bt[j].z, acc[i][j]);
          acc[i][j] = fmaf(a[i].w, bt[j].w, acc[i][j]);
        }
      }
    }
    #pragma unroll
    for (int i=0;i<4;++i)
      *(float4*)&Kg[b*4096 + (ti*4+i)*DD + tj*4] = make_float4(acc[i][0],acc[i][1],acc[i][2],acc[i][3]);
  }
}

// ===== K4: w' = y.K_b ; out = x + w'.P^T  (coalesced LDS-staged epilogue) =====
__global__ __launch_bounds__(256) void k_wout(const float* __restrict__ x, const short* __restrict__ Pbf,
                                              const short* __restrict__ ybf, const float* __restrict__ Kg,
                                              float* __restrict__ out){
  __shared__ float Ks[64*68];
  __shared__ float ys[16*68];
  __shared__ short wbf[16*72];
  __shared__ float os[2][16*68];
  const int tid  = threadIdx.x;
  const int lane = tid & 63, wid = tid >> 6;
  const int row0 = blockIdx.x * 16;
  const int bb   = row0 >> 10;
  const int m    = lane & 15, quad = lane >> 4;
  for (int idx = tid; idx < 4096; idx += 256)
    Ks[(idx>>6)*68 + (idx&63)] = Kg[bb*4096 + idx];
  {
    const int idx = tid*4;
    const int r = idx >> 6, c = idx & 63;
    bf16x4 yv = *(const bf16x4*)&ybf[(row0 + r)*DD + c];
    ys[r*68 + c    ] = htof(yv[0]);
    ys[r*68 + c + 1] = htof(yv[1]);
    ys[r*68 + c + 2] = htof(yv[2]);
    ys[r*68 + c + 3] = htof(yv[3]);
  }
  __syncthreads();
  {
    const int r = tid >> 4, c4 = (tid & 15)*4;
    float w0[4] = {0.f,0.f,0.f,0.f};
    for (int k = 0; k < 64; ++k){
      const float yr = ys[r*68 + k];
      const float4 kv = *(const float4*)&Ks[k*68 + c4];
      w0[0] = fmaf(yr, kv.x, w0[0]);
      w0[1] = fmaf(yr, kv.y, w0[1]);
      w0[2] = fmaf(yr, kv.z, w0[2]);
      w0[3] = fmaf(yr, kv.w, w0[3]);
    }
    bf16x4 pk;
    #pragma unroll
    for (int jj = 0; jj < 4; ++jj) pk[jj] = bfr(w0[jj]);
    *(bf16x4*)&wbf[r*72 + c4] = pk;
  }
  __syncthreads();
  // ---- phase 3: per it, the 4 waves cover 64 CONSECUTIVE cols [it*64, it*64+64).
  bf16x8 wa0 = *(const bf16x8*)&wbf[m*72 +      quad*8];
  bf16x8 wa1 = *(const bf16x8*)&wbf[m*72 + 32 + quad*8];
  const int er = tid >> 4;            // epilogue row 0..15
  const int ec = (tid & 15) * 4;      // epilogue col-in-chunk
  for (int it = 0; it < 18; ++it){
    const int n0 = it*64 + wid*16;
    bf16x8 ub0 = *(const bf16x8*)&Pbf[(n0 + m)*DD +      quad*8];
    bf16x8 ub1 = *(const bf16x8*)&Pbf[(n0 + m)*DD + 32 + quad*8];
    f32x4 acc = {0.f,0.f,0.f,0.f};
    acc = __builtin_amdgcn_mfma_f32_16x16x32_bf16(wa0, ub0, acc, 0, 0, 0);
    acc = __builtin_amdgcn_mfma_f32_16x16x32_bf16(wa1, ub1, acc, 0, 0, 0);
    float* ob = os[it & 1];
    #pragma unroll
    for (int q = 0; q < 4; ++q)
      ob[(quad*4 + q)*68 + wid*16 + m] = acc[q];
    __syncthreads();
    const float4 xv = *(const float4*)&x[(row0 + er)*NN + it*64 + ec];
    const float4 ov = *(const float4*)&ob[er*68 + ec];
    *(float4*)&out[(row0 + er)*NN + it*64 + ec] =
        make_float4(xv.x + ov.x, xv.y + ov.y, xv.z + ov.z, xv.w + ov.w);
  }
}

extern "C" void kernel_launch(void* const* d_in, const int* in_sizes, int n_in,
                              void* d_out, int out_size, void* d_ws, size_t ws_size,
                              hipStream_t stream) {
  const float* x    = (const float*)d_in[0];
  const float* cond = (const float*)d_in[1];
  const float* P    = (const float*)d_in[2];
  const float* W    = (const float*)d_in[3];
  const float* bias = (const float*)d_in[4];
  float* out = (float*)d_out;
  float* ws  = (float*)d_ws;

  float* Gpart = ws;                      // 24576 floats
  float* vpart = ws + 24576;              // 193536 floats (dead after k_fused)
  float* Kg    = ws + 24576;              // 65536 floats (aliases vpart; written by k_kmat)
  float* Mg    = ws + 218112;             // 65536 floats
  float* Rg    = ws + 283648;             // 4096 floats (R from QR)
  short* Pbf   = (short*)(ws + 287744);   // 1152*64 bf16
  short* Ptbf  = (short*)(ws + 324608);   // 64*1152 bf16
  short* ybf   = (short*)(ws + 361472);   // 16384*64 bf16

  hipLaunchKernelGGL(k_pre,  dim3(VBLKS + GPARTS + TBLKS), dim3(256), 0, stream,
                     cond, W, vpart, P, Gpart, Pbf, Ptbf);
  hipLaunchKernelGGL(k_fused, dim3(NB + 1 + NROWS/64), dim3(512), 0, stream,
                     Gpart, P, vpart, bias, Mg, Rg, x, Ptbf, ybf);
  hipLaunchKernelGGL(k_kmat, dim3(NB), dim3(256), 0, stream, Rg, Mg, Kg);
  hipLaunchKernelGGL(k_wout, dim3(NROWS/16), dim3(256), 0, stream, x, Pbf, ybf, Kg, out);
}